// Round 1
// baseline (124.628 us; speedup 1.0000x reference)
//
#include <hip/hip_runtime.h>

// trapezoid_mix: out[b,k] = (sum_n spectra[b,n]*trans[b,k,n]*w[n]) / nsmpl[k]
// w = [0.5, 1, ..., 1, 0.5]
//
// spectra: [4096, 4096] f32, trans: [4096, 10, 4096] f32, nsmpl: [10] f32
// out: [4096, 10] f32
//
// Memory-bound (738 MB read, ~117us roofline @6.3TB/s). One block per batch
// row; spectra row cached in registers (16 floats/thread) and reused across
// all 10 bands so trans is the only large stream, read exactly once via
// coalesced float4.

constexpr int NBANDS  = 10;
constexpr int NSMPL   = 4096;
constexpr int THREADS = 256;
constexpr int V4      = NSMPL / 4;        // 1024 float4 per row
constexpr int CHUNKS  = V4 / THREADS;     // 4 float4 per thread
constexpr int WAVES   = THREADS / 64;     // 4

__global__ __launch_bounds__(THREADS)
void trapmix_kernel(const float* __restrict__ spectra,
                    const float* __restrict__ trans,
                    const float* __restrict__ nsmpl_per_band,
                    float* __restrict__ out)
{
    const int b    = blockIdx.x;
    const int tid  = threadIdx.x;
    const int lane = tid & 63;
    const int wave = tid >> 6;

    // ---- cache this row's spectra in registers (coalesced float4) ----
    const float4* sp = reinterpret_cast<const float4*>(spectra + (size_t)b * NSMPL);
    float4 s[CHUNKS];
#pragma unroll
    for (int c = 0; c < CHUNKS; ++c)
        s[c] = sp[tid + c * THREADS];

    // fold trapezoid half-weights into the cached spectra
    if (tid == 0)           s[0].x          *= 0.5f;   // sample 0
    if (tid == THREADS - 1) s[CHUNKS - 1].w *= 0.5f;   // sample NSMPL-1

    const float4* tr = reinterpret_cast<const float4*>(
        trans + (size_t)b * NBANDS * NSMPL);

    // ---- accumulate per-band dot products ----
    float acc[NBANDS];
    for (int k = 0; k < NBANDS; ++k) {
        float v = 0.0f;
#pragma unroll
        for (int c = 0; c < CHUNKS; ++c) {
            float4 t4 = tr[(size_t)k * V4 + tid + c * THREADS];
            v += t4.x * s[c].x;
            v += t4.y * s[c].y;
            v += t4.z * s[c].z;
            v += t4.w * s[c].w;
        }
        acc[k] = v;
    }

    // ---- reduce: 64-lane shuffle tree, then cross-wave via LDS ----
    __shared__ float red[WAVES][NBANDS];
#pragma unroll
    for (int k = 0; k < NBANDS; ++k) {
        float v = acc[k];
#pragma unroll
        for (int off = 32; off > 0; off >>= 1)
            v += __shfl_down(v, off, 64);
        if (lane == 0) red[wave][k] = v;
    }
    __syncthreads();

    if (tid < NBANDS) {
        float sum = 0.0f;
#pragma unroll
        for (int wv = 0; wv < WAVES; ++wv)
            sum += red[wv][tid];
        out[(size_t)b * NBANDS + tid] = sum / nsmpl_per_band[tid];
    }
}

extern "C" void kernel_launch(void* const* d_in, const int* in_sizes, int n_in,
                              void* d_out, int out_size, void* d_ws, size_t ws_size,
                              hipStream_t stream)
{
    const float* spectra = (const float*)d_in[0];
    const float* trans   = (const float*)d_in[1];
    const float* nsmpl   = (const float*)d_in[2];
    float* out           = (float*)d_out;

    const int bsz = in_sizes[0] / NSMPL;   // 4096

    trapmix_kernel<<<bsz, THREADS, 0, stream>>>(spectra, trans, nsmpl, out);
}

// Round 3
// 108.791 us; speedup vs baseline: 1.1456x; 1.1456x over previous
//
#include <hip/hip_runtime.h>

// trapezoid_mix: out[b,k] = (sum_n spectra[b,n]*trans[b,k,n]*w[n]) / nsmpl[k]
// w = [0.5, 1, ..., 1, 0.5]
//
// spectra: [4096, 4096] f32, trans: [4096, 10, 4096] f32, nsmpl: [10] f32
// out: [4096, 10] f32
//
// Memory-bound (738 MB read, ~117us roofline @6.3TB/s). One block per batch
// row; spectra row cached in registers (16 floats/thread) and reused across
// all 10 bands so trans is the only large stream, read exactly once.
// R3: nontemporal loads via clang ext_vector float4 (HIP_vector_type is a
// struct and is rejected by the builtin), k-loop unrolled x2 for deeper MLP.

typedef float f32x4 __attribute__((ext_vector_type(4)));

constexpr int NBANDS  = 10;
constexpr int NSMPL   = 4096;
constexpr int THREADS = 256;
constexpr int V4      = NSMPL / 4;        // 1024 float4 per row
constexpr int CHUNKS  = V4 / THREADS;     // 4 float4 per thread
constexpr int WAVES   = THREADS / 64;     // 4

__global__ __launch_bounds__(THREADS)
void trapmix_kernel(const float* __restrict__ spectra,
                    const float* __restrict__ trans,
                    const float* __restrict__ nsmpl_per_band,
                    float* __restrict__ out)
{
    const int b    = blockIdx.x;
    const int tid  = threadIdx.x;
    const int lane = tid & 63;
    const int wave = tid >> 6;

    // ---- cache this row's spectra in registers (coalesced float4) ----
    const f32x4* sp = reinterpret_cast<const f32x4*>(spectra + (size_t)b * NSMPL);
    f32x4 s[CHUNKS];
#pragma unroll
    for (int c = 0; c < CHUNKS; ++c)
        s[c] = __builtin_nontemporal_load(&sp[tid + c * THREADS]);

    // fold trapezoid half-weights into the cached spectra
    if (tid == 0)           s[0].x          *= 0.5f;   // sample 0
    if (tid == THREADS - 1) s[CHUNKS - 1].w *= 0.5f;   // sample NSMPL-1

    const f32x4* tr = reinterpret_cast<const f32x4*>(
        trans + (size_t)b * NBANDS * NSMPL);

    // ---- accumulate per-band dot products, 2 bands at a time ----
    float acc[NBANDS];
#pragma unroll
    for (int k = 0; k < NBANDS; k += 2) {
        float v0 = 0.0f, v1 = 0.0f;
        f32x4 t0[CHUNKS], t1[CHUNKS];
#pragma unroll
        for (int c = 0; c < CHUNKS; ++c) {
            t0[c] = __builtin_nontemporal_load(&tr[(size_t)(k    ) * V4 + tid + c * THREADS]);
            t1[c] = __builtin_nontemporal_load(&tr[(size_t)(k + 1) * V4 + tid + c * THREADS]);
        }
#pragma unroll
        for (int c = 0; c < CHUNKS; ++c) {
            v0 += t0[c].x * s[c].x;
            v0 += t0[c].y * s[c].y;
            v0 += t0[c].z * s[c].z;
            v0 += t0[c].w * s[c].w;
            v1 += t1[c].x * s[c].x;
            v1 += t1[c].y * s[c].y;
            v1 += t1[c].z * s[c].z;
            v1 += t1[c].w * s[c].w;
        }
        acc[k]     = v0;
        acc[k + 1] = v1;
    }

    // ---- reduce: 64-lane shuffle tree, then cross-wave via LDS ----
    __shared__ float red[WAVES][NBANDS];
#pragma unroll
    for (int k = 0; k < NBANDS; ++k) {
        float v = acc[k];
#pragma unroll
        for (int off = 32; off > 0; off >>= 1)
            v += __shfl_down(v, off, 64);
        if (lane == 0) red[wave][k] = v;
    }
    __syncthreads();

    if (tid < NBANDS) {
        float sum = 0.0f;
#pragma unroll
        for (int wv = 0; wv < WAVES; ++wv)
            sum += red[wv][tid];
        out[(size_t)b * NBANDS + tid] = sum / nsmpl_per_band[tid];
    }
}

extern "C" void kernel_launch(void* const* d_in, const int* in_sizes, int n_in,
                              void* d_out, int out_size, void* d_ws, size_t ws_size,
                              hipStream_t stream)
{
    const float* spectra = (const float*)d_in[0];
    const float* trans   = (const float*)d_in[1];
    const float* nsmpl   = (const float*)d_in[2];
    float* out           = (float*)d_out;

    const int bsz = in_sizes[0] / NSMPL;   // 4096

    trapmix_kernel<<<bsz, THREADS, 0, stream>>>(spectra, trans, nsmpl, out);
}